// Round 5
// baseline (465.272 us; speedup 1.0000x reference)
//
#include <hip/hip_runtime.h>
#include <math.h>

// ---------------- weight transpose: w[co][ci][kh][kw] -> wt[ci][kh][kw][co] -----------
__global__ void kprep(const float* __restrict__ w2, const float* __restrict__ w3,
                      const float* __restrict__ w4, float* __restrict__ w2t,
                      float* __restrict__ w3t, float* __restrict__ w4t) {
  int i = blockIdx.x * 256 + threadIdx.x;
  if (i < 52500) {            // w2,w4: 50*50*3*7
    int co = i % 50, r = i / 50;
    w2t[i] = w2[co * 1050 + r];
    w4t[i] = w4[co * 1050 + r];
  } else {
    int j = i - 52500;
    if (j < 37500) {          // w3: 50*50*3*5
      int co = j % 50, r = j / 50;
      w3t[j] = w3[co * 750 + r];
    }
  }
}

// ---------------- K1: conv1 (1ci->co, 3x7 circular, 64x256) + maxpool 2x4 + relu -----
// grid (8 rowgrp, 10 cochunk, 32 img) x 256 thr; 5 co per block -> 10 waves/SIMD queued
__global__ __launch_bounds__(256) void k1(const float* __restrict__ x,
                                          const float* __restrict__ w1,
                                          const float* __restrict__ b1,
                                          float* __restrict__ a1) {
  int b = blockIdx.z;
  int pr0 = blockIdx.x * 4;
  int co0 = blockIdx.y * 5;
  int ty = threadIdx.x >> 6;
  int pc = threadIdx.x & 63;
  int pr = pr0 + ty;
  const float* xb = x + b * (64 * 256);
  float xw[4][10];
#pragma unroll
  for (int r = 0; r < 4; ++r) {
    int row = (2 * pr - 2 + r) & 63;
#pragma unroll
    for (int c = 0; c < 10; ++c) {
      int col = (4 * pc - 6 + c) & 255;
      xw[r][c] = xb[row * 256 + col];
    }
  }
#pragma unroll
  for (int cq = 0; cq < 5; ++cq) {
    int co = co0 + cq;
    const float* wp = w1 + co * 21;      // block-uniform -> scalar loads
    float m = -1e30f;
#pragma unroll
    for (int iy = 0; iy < 2; ++iy) {
#pragma unroll
      for (int jx = 0; jx < 4; ++jx) {
        float s = 0.f;
#pragma unroll
        for (int di = 0; di < 3; ++di)
#pragma unroll
          for (int dj = 0; dj < 7; ++dj)
            s = fmaf(xw[iy + 2 - di][jx + 6 - dj], wp[di * 7 + dj], s);
        m = fmaxf(m, s);
      }
    }
    float v = fmaxf(m + b1[co], 0.f);
    a1[((b * 50 + co) * 32 + pr) * 64 + pc] = v;
  }
}

// ---------------- K2: conv2 (50->50, 3x7 circular, 32x64) + maxpool 2x4 + relu -------
// Single-stage design: LDS holds ALL 50 ci x 4 rows x 70 padded cols (56 KB), staged
// once -> ONE barrier pair, then 50ci x 21tap x 25co = 26250 FMAs uninterrupted.
// 256 thr = 2 rows x 64 cols x 2 co-halves (h readfirstlane'd -> s_load weights;
// R3 lesson: threadIdx-derived weight addr kills the scalar path).
// 2 blocks/CU (LDS-capped) = 2 waves/SIMD: occupancy deliberately low, VALU-dense.
__global__ __launch_bounds__(256) void k2(const float* __restrict__ a1,
                                          const float* __restrict__ w2t,
                                          const float* __restrict__ b2,
                                          float* __restrict__ a2) {
  __shared__ float sm[14000];     // [ci50][rr4][p70], p-6 = col mod 64
  int b = blockIdx.y;
  int r0 = blockIdx.x * 2;        // pre-pool rows r0, r0+1
  int tid = threadIdx.x;
  int lane = tid & 63;            // xcol
  int y = (tid >> 6) & 1;         // row offset (wave-uniform; LDS vaddr only)
  int h = __builtin_amdgcn_readfirstlane(tid >> 7);   // co half 0/1, forced SGPR
  const float* ain = a1 + b * (50 * 2048);
  for (int e = tid; e < 14000; e += 256) {
    int ci = e / 280;
    int rem = e - ci * 280;
    int rr = rem / 70;
    int p = rem - rr * 70;
    int row = (r0 - 2 + rr) & 31;
    int col = (p - 6) & 63;
    sm[e] = ain[ci * 2048 + row * 64 + col];
  }
  float acc[25];
#pragma unroll
  for (int c = 0; c < 25; ++c) acc[c] = b2[h * 25 + c];
  __syncthreads();
#pragma unroll 1
  for (int ci = 0; ci < 50; ++ci) {
    const float* sp = sm + ci * 280 + y * 70 + lane;      // one vaddr per ci
    const float* wp = w2t + ci * 1050 + h * 25;           // scalar base
#pragma unroll
    for (int di = 0; di < 3; ++di) {
#pragma unroll
      for (int dj = 0; dj < 7; ++dj) {
        float xv = sp[(2 - di) * 70 + (6 - dj)];          // immediate offset
        const float* wrow = wp + (di * 7 + dj) * 50;      // wave-uniform
#pragma unroll
        for (int c = 0; c < 25; ++c)
          acc[c] = fmaf(xv, wrow[c], acc[c]);
      }
    }
  }
  // pool 2x4 + relu through LDS (reuse sm)
  __syncthreads();
#pragma unroll
  for (int c = 0; c < 25; ++c)
    sm[(h * 25 + c) * 128 + y * 64 + lane] = acc[c];
  __syncthreads();
  for (int w = tid; w < 800; w += 256) {
    int co = w >> 4;
    int pc = w & 15;
    float m = -1e30f;
#pragma unroll
    for (int yy = 0; yy < 2; ++yy)
#pragma unroll
      for (int xx = 0; xx < 4; ++xx)
        m = fmaxf(m, sm[co * 128 + yy * 64 + pc * 4 + xx]);
    m = fmaxf(m, 0.f);
    a2[((b * 50 + co) * 16 + blockIdx.x) * 16 + pc] = m;
  }
}

// ---------------- K3: combine(even + mean(odd)) -> upsample(2,4)-sparse conv3 (3x5) + relu
// grid (4 rowgrp, 10 cochunk, 16 img) x 512 thr. acc[5]. Padded LDS [50][5][17].
__global__ __launch_bounds__(512) void k3(const float* __restrict__ a2,
                                          const float* __restrict__ w3t,
                                          const float* __restrict__ b3,
                                          float* __restrict__ a3) {
  __shared__ float ts[4250];     // [ci50][rr5][p17], p-1 = col mod 16
  __shared__ float mean_s[64];
  __shared__ float part[200];
  int b = blockIdx.z;
  int r0 = blockIdx.x * 8;       // output rows r0..r0+7
  int co0 = blockIdx.y * 5;
  int tid = threadIdx.x;
  const float* aodd = a2 + (2 * b + 1) * (50 * 256);
  if (tid < 200) {
    int ci = tid >> 2, pp = tid & 3;
    float s = 0.f;
    for (int k = 0; k < 64; ++k) s += aodd[ci * 256 + pp * 64 + k];
    part[tid] = s;
  }
  __syncthreads();
  if (tid < 50)
    mean_s[tid] = (part[4 * tid] + part[4 * tid + 1] + part[4 * tid + 2] + part[4 * tid + 3]) * (1.f / 256.f);
  __syncthreads();
  const float* aev = a2 + (2 * b) * (50 * 256);
  for (int e = tid; e < 4250; e += 512) {
    int ci = e / 85;
    int rem = e - ci * 85;
    int rr = rem / 17;
    int p = rem - rr * 17;
    int trow = ((r0 >> 1) - 1 + rr) & 15;
    int col = (p - 1) & 15;
    ts[e] = aev[ci * 256 + trow * 16 + col] + mean_s[ci];
  }
  __syncthreads();
  int wv = __builtin_amdgcn_readfirstlane(tid >> 6);   // 0..7
  int lane = tid & 63;
  int pcls = wv >> 2;            // row parity class (SGPR)
  int m = wv & 3;                // j%4 class (SGPR)
  int q = lane & 15;
  int yidx = lane >> 4;
  int i = r0 + 2 * yidx + pcls;
  int j = 4 * q + m;
  float acc[5];
#pragma unroll
  for (int c = 0; c < 5; ++c) acc[c] = b3[co0 + c];
  int ndi = (pcls == 0) ? 2 : 1;
  int ndj = (m == 0) ? 2 : 1;
  for (int ci = 0; ci < 50; ++ci) {
    const float* sp = ts + ci * 85 + yidx * 17 + q;    // one vaddr per ci
    const float* wp = w3t + ci * 750 + co0;
    for (int aa = 0; aa < ndi; ++aa) {
      int di = (pcls == 0) ? (2 * aa) : 1;
      int rro = 1 - (di >> 1);
      for (int e2 = 0; e2 < ndj; ++e2) {
        int dj = (m == 0) ? (4 * e2) : m;
        float xv = sp[rro * 17 + 1 - e2];              // immediate offset (wave-uniform)
        const float* wrow = wp + (di * 5 + dj) * 50;   // wave-uniform
#pragma unroll
        for (int c = 0; c < 5; ++c)
          acc[c] = fmaf(xv, wrow[c], acc[c]);
      }
    }
  }
  float* aout = a3 + b * (50 * 2048);
#pragma unroll
  for (int c = 0; c < 5; ++c)
    aout[(co0 + c) * 2048 + i * 64 + j] = fmaxf(acc[c], 0.f);
}

// ---------------- K4: upsample(2,4)-sparse conv4 (3x7, 64x256) + relu ----------------
// grid (32 rowgrp, 5 cochunk, 16 img) x 512 thr. acc[10]. Padded LDS [50][2][65].
__global__ __launch_bounds__(512) void k4(const float* __restrict__ a3,
                                          const float* __restrict__ w4t,
                                          const float* __restrict__ b4,
                                          float* __restrict__ a4) {
  __shared__ float s4[6500];     // [ci50][rr2][p65], p-1 = col mod 64
  int b = blockIdx.z;
  int r0 = blockIdx.x * 2;       // output rows r0, r0+1
  int co0 = blockIdx.y * 10;
  int tid = threadIdx.x;
  const float* ain = a3 + b * (50 * 2048);
  for (int e = tid; e < 6500; e += 512) {
    int ci = e / 130;
    int rem = e - ci * 130;
    int rr = rem / 65;
    int p = rem - rr * 65;
    int row = ((r0 >> 1) - 1 + rr) & 31;
    int col = (p - 1) & 63;
    s4[e] = ain[ci * 2048 + row * 64 + col];
  }
  __syncthreads();
  int wv = __builtin_amdgcn_readfirstlane(tid >> 6);  // 0..7
  int lane = tid & 63;
  int rowsel = wv >> 2;
  int m = wv & 3;
  int i = r0 + rowsel;
  int j = 4 * lane + m;
  float acc[10];
#pragma unroll
  for (int co = 0; co < 10; ++co) acc[co] = b4[co0 + co];
  int ndi = (rowsel == 0) ? 2 : 1;
  int ndj = (m < 3) ? 2 : 1;
  for (int ci = 0; ci < 50; ++ci) {
    const float* sp = s4 + ci * 130 + lane;            // one vaddr per ci
    const float* wp = w4t + ci * 1050 + co0;
    for (int aa = 0; aa < ndi; ++aa) {
      int di = (rowsel == 0) ? (2 * aa) : 1;
      int rro = 1 - (di >> 1);
      for (int e2 = 0; e2 < ndj; ++e2) {
        int dj = m + 4 * e2;
        float xv = sp[rro * 65 + 1 - e2];              // immediate offset (wave-uniform)
        const float* wrow = wp + (di * 7 + dj) * 50;   // wave-uniform
#pragma unroll
        for (int co = 0; co < 10; ++co)
          acc[co] = fmaf(xv, wrow[co], acc[co]);
      }
    }
  }
  float* aout = a4 + b * (50 * 16384);
#pragma unroll
  for (int co = 0; co < 10; ++co)
    aout[(co0 + co) * 16384 + i * 256 + j] = fmaxf(acc[co], 0.f);
}

// ---------------- K5a: conv5 partial over 10-ci slice (3x7 circular, 64x256) ---------
// grid (16 rowgrp, 5 cislice, 16 img) x 256 thr -> 5 waves/SIMD.
__global__ __launch_bounds__(256) void k5a(const float* __restrict__ a4,
                                           const float* __restrict__ w5,
                                           float* __restrict__ p5) {
  __shared__ __align__(16) float s5[7920];   // [ci5][rr6][c264], c-8 = col mod 256
  int b = blockIdx.z;
  int r0 = blockIdx.x * 4;
  int cs = blockIdx.y;           // ci slice: [cs*10, cs*10+10)
  int tid = threadIdx.x;
  int y = tid >> 6;
  int q = tid & 63;
  int j0 = q * 4;
  float acc0 = 0.f, acc1 = 0.f, acc2 = 0.f, acc3 = 0.f;
  const float* ain = a4 + b * (50 * 16384) + cs * 10 * 16384;
  for (int cc = 0; cc < 2; ++cc) {           // ci chunks of 5
    __syncthreads();
    for (int e = tid; e < 7920; e += 256) {
      int ci = e / 1584;
      int rr = (e / 264) % 6;
      int c = e % 264;
      int row = (r0 - 2 + rr) & 63;
      int col = (c - 8) & 255;
      s5[e] = ain[(cc * 5 + ci) * 16384 + row * 256 + col];
    }
    __syncthreads();
#pragma unroll
    for (int ci = 0; ci < 5; ++ci) {
#pragma unroll
      for (int di = 0; di < 3; ++di) {
        const float4* prow = (const float4*)&s5[ci * 1584 + (y + 2 - di) * 264 + j0];
        float4 v0 = prow[0], v1 = prow[1], v2 = prow[2];
        float wnd[12] = {v0.x, v0.y, v0.z, v0.w, v1.x, v1.y, v1.z, v1.w,
                         v2.x, v2.y, v2.z, v2.w};
        const float* wp = w5 + ((cs * 10 + cc * 5 + ci) * 3 + di) * 7;  // wave-uniform
#pragma unroll
        for (int dj = 0; dj < 7; ++dj) {
          float wgt = wp[dj];
          acc0 = fmaf(wnd[8 - dj], wgt, acc0);
          acc1 = fmaf(wnd[9 - dj], wgt, acc1);
          acc2 = fmaf(wnd[10 - dj], wgt, acc2);
          acc3 = fmaf(wnd[11 - dj], wgt, acc3);
        }
      }
    }
  }
  float4 r = {acc0, acc1, acc2, acc3};
  *(float4*)(p5 + (cs * 16 + b) * 16384 + (r0 + y) * 256 + j0) = r;
}

// ---------------- K5b: sum 5 partials + bias + sigmoid -------------------------------
__global__ __launch_bounds__(256) void k5b(const float* __restrict__ p5,
                                           const float* __restrict__ b5,
                                           float* __restrict__ out) {
  int i = blockIdx.x * 256 + threadIdx.x;    // 65536 float4 positions
  int b = i >> 12;                           // image
  int off = i & 4095;                        // float4 offset within image
  const float4* p4 = (const float4*)p5;
  float bias = b5[0];
  float4 s = {bias, bias, bias, bias};
#pragma unroll
  for (int cs = 0; cs < 5; ++cs) {
    float4 v = p4[(cs * 16 + b) * 4096 + off];
    s.x += v.x; s.y += v.y; s.z += v.z; s.w += v.w;
  }
  float4 r;
  r.x = 1.f / (1.f + expf(-s.x));
  r.y = 1.f / (1.f + expf(-s.y));
  r.z = 1.f / (1.f + expf(-s.z));
  r.w = 1.f / (1.f + expf(-s.w));
  ((float4*)out)[i] = r;
}

extern "C" void kernel_launch(void* const* d_in, const int* in_sizes, int n_in,
                              void* d_out, int out_size, void* d_ws, size_t ws_size,
                              hipStream_t stream) {
  (void)in_sizes; (void)n_in; (void)out_size; (void)ws_size;
  const float* x  = (const float*)d_in[0];
  const float* w1 = (const float*)d_in[1];
  const float* b1 = (const float*)d_in[2];
  const float* w2 = (const float*)d_in[3];
  const float* b2 = (const float*)d_in[4];
  const float* w3 = (const float*)d_in[5];
  const float* b3 = (const float*)d_in[6];
  const float* w4 = (const float*)d_in[7];
  const float* b4 = (const float*)d_in[8];
  const float* w5 = (const float*)d_in[9];
  const float* b5 = (const float*)d_in[10];
  float* out = (float*)d_out;
  float* ws  = (float*)d_ws;
  float* w2t = ws;                       // 52500
  float* w3t = w2t + 52500;              // 37500
  float* w4t = w3t + 37500;              // 52500
  float* a1  = w4t + 52500;              // 32*50*32*64  = 3,276,800
  float* a2  = a1 + 32 * 50 * 32 * 64;   // 32*50*16*16  = 409,600
  float* a3  = a2 + 32 * 50 * 16 * 16;   // 16*50*32*64  = 1,638,400
  float* a4  = a3 + 16 * 50 * 32 * 64;   // 16*50*64*256 = 13,107,200
  float* p5  = a4 + 16 * 50 * 64 * 256;  // 5*16*64*256  = 1,310,720
  hipLaunchKernelGGL(kprep, dim3(352), dim3(256), 0, stream, w2, w3, w4, w2t, w3t, w4t);
  hipLaunchKernelGGL(k1, dim3(8, 10, 32), dim3(256), 0, stream, x, w1, b1, a1);
  hipLaunchKernelGGL(k2, dim3(16, 32), dim3(256), 0, stream, a1, w2t, b2, a2);
  hipLaunchKernelGGL(k3, dim3(4, 10, 16), dim3(512), 0, stream, a2, w3t, b3, a3);
  hipLaunchKernelGGL(k4, dim3(32, 5, 16), dim3(512), 0, stream, a3, w4t, b4, a4);
  hipLaunchKernelGGL(k5a, dim3(16, 5, 16), dim3(256), 0, stream, a4, w5, p5);
  hipLaunchKernelGGL(k5b, dim3(256), dim3(256), 0, stream, p5, b5, out);
}

// Round 6
// 397.441 us; speedup vs baseline: 1.1707x; 1.1707x over previous
//
#include <hip/hip_runtime.h>
#include <math.h>

// ---------------- weight transpose: w[co][ci][kh][kw] -> wt[ci][kh][kw][co] -----------
__global__ void kprep(const float* __restrict__ w2, const float* __restrict__ w3,
                      const float* __restrict__ w4, float* __restrict__ w2t,
                      float* __restrict__ w3t, float* __restrict__ w4t) {
  int i = blockIdx.x * 256 + threadIdx.x;
  if (i < 52500) {            // w2,w4: 50*50*3*7
    int co = i % 50, r = i / 50;
    w2t[i] = w2[co * 1050 + r];
    w4t[i] = w4[co * 1050 + r];
  } else {
    int j = i - 52500;
    if (j < 37500) {          // w3: 50*50*3*5
      int co = j % 50, r = j / 50;
      w3t[j] = w3[co * 750 + r];
    }
  }
}

// ---------------- K1: conv1 (1ci->co, 3x7 circular, 64x256) + maxpool 2x4 + relu -----
// grid (16 rowgrp, 5 cogrp, 32 img) x 256 thr = 2560 blocks -> 10 waves/SIMD queued.
// Each wave: 2 pooled rows x 64 cols, 5 co. Co split across waves via readfirstlane
// (R3 lesson: threadIdx-derived weight addresses kill the scalar-load path).
__global__ __launch_bounds__(256) void k1(const float* __restrict__ x,
                                          const float* __restrict__ w1,
                                          const float* __restrict__ b1,
                                          float* __restrict__ a1) {
  int b = blockIdx.z;
  int pr0 = blockIdx.x * 2;
  int wv = __builtin_amdgcn_readfirstlane(threadIdx.x >> 6);  // 0..3
  int pc = threadIdx.x & 63;
  int pr = pr0 + (wv & 1);
  int co0 = blockIdx.y * 10 + (wv >> 1) * 5;   // SGPR
  const float* xb = x + b * (64 * 256);
  float xw[4][10];
#pragma unroll
  for (int r = 0; r < 4; ++r) {
    int row = (2 * pr - 2 + r) & 63;
#pragma unroll
    for (int c = 0; c < 10; ++c) {
      int col = (4 * pc - 6 + c) & 255;
      xw[r][c] = xb[row * 256 + col];
    }
  }
#pragma unroll
  for (int cq = 0; cq < 5; ++cq) {
    int co = co0 + cq;
    const float* wp = w1 + co * 21;      // wave-uniform -> scalar loads
    float m = -1e30f;
#pragma unroll
    for (int iy = 0; iy < 2; ++iy) {
#pragma unroll
      for (int jx = 0; jx < 4; ++jx) {
        float s = 0.f;
#pragma unroll
        for (int di = 0; di < 3; ++di)
#pragma unroll
          for (int dj = 0; dj < 7; ++dj)
            s = fmaf(xw[iy + 2 - di][jx + 6 - dj], wp[di * 7 + dj], s);
        m = fmaxf(m, s);
      }
    }
    float v = fmaxf(m + b1[co], 0.f);
    a1[((b * 50 + co) * 32 + pr) * 64 + pc] = v;
  }
}

// ---------------- K2: conv2 partial over 25-ci half (3x7 circular, 32x64) ------------
// R2-proven inner shape (acc[10], 10-ci LDS chunks, VGPR~28, 15.4KB LDS) but ci split
// 2-way -> 2560 blocks = ~8 resident waves/SIMD for s_load latency hiding.
// Partials (no bias/pool) go to p2; k2b combines.
__global__ __launch_bounds__(256) void k2(const float* __restrict__ a1,
                                          const float* __restrict__ w2t,
                                          float* __restrict__ p2) {
  __shared__ float sm[3840];       // [ci<=10][rr6][col64]
  int hh = blockIdx.z & 1;         // ci half
  int b = blockIdx.z >> 1;         // image
  int r0 = blockIdx.x * 4;         // conv rows r0..r0+3
  int co0 = blockIdx.y * 10;
  int ci0 = hh * 25;
  int y = threadIdx.x >> 6;        // 0..3
  int xcol = threadIdx.x & 63;
  float acc[10];
#pragma unroll
  for (int c = 0; c < 10; ++c) acc[c] = 0.f;
  const float* ain = a1 + b * (50 * 2048);
  for (int cc = 0; cc < 3; ++cc) {           // ci chunks {10,10,5}
    int n = (cc < 2) ? 10 : 5;
    __syncthreads();
    for (int e = threadIdx.x; e < n * 384; e += 256) {   // [ci][rr6][col64]
      int ci = e / 384;
      int rr = (e >> 6) % 6;
      int col = e & 63;
      int row = (r0 - 2 + rr) & 31;
      sm[e] = ain[(ci0 + cc * 10 + ci) * 2048 + row * 64 + col];
    }
    __syncthreads();
    for (int ci = 0; ci < n; ++ci) {
      const float* sin_ = sm + ci * 384;
      const float* wbase = w2t + (ci0 + cc * 10 + ci) * 1050 + co0;
#pragma unroll
      for (int di = 0; di < 3; ++di) {
        const float* srow = sin_ + (y + 2 - di) * 64;
#pragma unroll
        for (int dj = 0; dj < 7; ++dj) {
          float xv = srow[(xcol - dj) & 63];
          const float* wrow = wbase + (di * 7 + dj) * 50;  // wave-uniform
#pragma unroll
          for (int c = 0; c < 10; ++c)
            acc[c] = fmaf(xv, wrow[c], acc[c]);
        }
      }
    }
  }
  float* pout = p2 + ((hh * 32 + b) * 50 + co0) * 2048 + (r0 + y) * 64 + xcol;
#pragma unroll
  for (int c = 0; c < 10; ++c)
    pout[c * 2048] = acc[c];
}

// ---------------- K2b: sum 2 ci-halves + bias + maxpool 2x4 + relu -------------------
__global__ __launch_bounds__(256) void k2b(const float* __restrict__ p2,
                                           const float* __restrict__ b2,
                                           float* __restrict__ a2) {
  int idx = blockIdx.x * 256 + threadIdx.x;  // 409600 outputs
  int pc = idx & 15;
  int pr = (idx >> 4) & 15;
  int t = idx >> 8;
  int co = t % 50;
  int b = t / 50;
  int i0 = ((b) * 50 + co) * 2048 + (2 * pr) * 64 + 4 * pc;
  int i1 = i0 + 32 * 50 * 2048;
  float bias = b2[co];
  float m = -1e30f;
#pragma unroll
  for (int yy = 0; yy < 2; ++yy)
#pragma unroll
    for (int xx = 0; xx < 4; ++xx) {
      int o = yy * 64 + xx;
      m = fmaxf(m, p2[i0 + o] + p2[i1 + o] + bias);
    }
  a2[((b * 50 + co) * 16 + pr) * 16 + pc] = fmaxf(m, 0.f);
}

// ---------------- K3: combine(even + mean(odd)) -> upsample(2,4)-sparse conv3 (3x5) + relu
// grid (4 rowgrp, 10 cochunk, 16 img) x 512 thr. acc[5]. Padded LDS [50][5][17].
__global__ __launch_bounds__(512) void k3(const float* __restrict__ a2,
                                          const float* __restrict__ w3t,
                                          const float* __restrict__ b3,
                                          float* __restrict__ a3) {
  __shared__ float ts[4250];     // [ci50][rr5][p17], p-1 = col mod 16
  __shared__ float mean_s[64];
  __shared__ float part[200];
  int b = blockIdx.z;
  int r0 = blockIdx.x * 8;       // output rows r0..r0+7
  int co0 = blockIdx.y * 5;
  int tid = threadIdx.x;
  const float* aodd = a2 + (2 * b + 1) * (50 * 256);
  if (tid < 200) {
    int ci = tid >> 2, pp = tid & 3;
    float s = 0.f;
    for (int k = 0; k < 64; ++k) s += aodd[ci * 256 + pp * 64 + k];
    part[tid] = s;
  }
  __syncthreads();
  if (tid < 50)
    mean_s[tid] = (part[4 * tid] + part[4 * tid + 1] + part[4 * tid + 2] + part[4 * tid + 3]) * (1.f / 256.f);
  __syncthreads();
  const float* aev = a2 + (2 * b) * (50 * 256);
  for (int e = tid; e < 4250; e += 512) {
    int ci = e / 85;
    int rem = e - ci * 85;
    int rr = rem / 17;
    int p = rem - rr * 17;
    int trow = ((r0 >> 1) - 1 + rr) & 15;
    int col = (p - 1) & 15;
    ts[e] = aev[ci * 256 + trow * 16 + col] + mean_s[ci];
  }
  __syncthreads();
  int wv = __builtin_amdgcn_readfirstlane(tid >> 6);   // 0..7
  int lane = tid & 63;
  int pcls = wv >> 2;            // row parity class (SGPR)
  int m = wv & 3;                // j%4 class (SGPR)
  int q = lane & 15;
  int yidx = lane >> 4;
  int i = r0 + 2 * yidx + pcls;
  int j = 4 * q + m;
  float acc[5];
#pragma unroll
  for (int c = 0; c < 5; ++c) acc[c] = b3[co0 + c];
  int ndi = (pcls == 0) ? 2 : 1;
  int ndj = (m == 0) ? 2 : 1;
  for (int ci = 0; ci < 50; ++ci) {
    const float* sp = ts + ci * 85 + yidx * 17 + q;    // one vaddr per ci
    const float* wp = w3t + ci * 750 + co0;
    for (int aa = 0; aa < ndi; ++aa) {
      int di = (pcls == 0) ? (2 * aa) : 1;
      int rro = 1 - (di >> 1);
      for (int e2 = 0; e2 < ndj; ++e2) {
        int dj = (m == 0) ? (4 * e2) : m;
        float xv = sp[rro * 17 + 1 - e2];              // immediate offset (wave-uniform)
        const float* wrow = wp + (di * 5 + dj) * 50;   // wave-uniform
#pragma unroll
        for (int c = 0; c < 5; ++c)
          acc[c] = fmaf(xv, wrow[c], acc[c]);
      }
    }
  }
  float* aout = a3 + b * (50 * 2048);
#pragma unroll
  for (int c = 0; c < 5; ++c)
    aout[(co0 + c) * 2048 + i * 64 + j] = fmaxf(acc[c], 0.f);
}

// ---------------- K4: upsample(2,4)-sparse conv4 (3x7, 64x256) + relu ----------------
// grid (32 rowgrp, 5 cochunk, 16 img) x 512 thr. acc[10]. Padded LDS [50][2][65].
__global__ __launch_bounds__(512) void k4(const float* __restrict__ a3,
                                          const float* __restrict__ w4t,
                                          const float* __restrict__ b4,
                                          float* __restrict__ a4) {
  __shared__ float s4[6500];     // [ci50][rr2][p65], p-1 = col mod 64
  int b = blockIdx.z;
  int r0 = blockIdx.x * 2;       // output rows r0, r0+1
  int co0 = blockIdx.y * 10;
  int tid = threadIdx.x;
  const float* ain = a3 + b * (50 * 2048);
  for (int e = tid; e < 6500; e += 512) {
    int ci = e / 130;
    int rem = e - ci * 130;
    int rr = rem / 65;
    int p = rem - rr * 65;
    int row = ((r0 >> 1) - 1 + rr) & 31;
    int col = (p - 1) & 63;
    s4[e] = ain[ci * 2048 + row * 64 + col];
  }
  __syncthreads();
  int wv = __builtin_amdgcn_readfirstlane(tid >> 6);  // 0..7
  int lane = tid & 63;
  int rowsel = wv >> 2;
  int m = wv & 3;
  int i = r0 + rowsel;
  int j = 4 * lane + m;
  float acc[10];
#pragma unroll
  for (int co = 0; co < 10; ++co) acc[co] = b4[co0 + co];
  int ndi = (rowsel == 0) ? 2 : 1;
  int ndj = (m < 3) ? 2 : 1;
  for (int ci = 0; ci < 50; ++ci) {
    const float* sp = s4 + ci * 130 + lane;            // one vaddr per ci
    const float* wp = w4t + ci * 1050 + co0;
    for (int aa = 0; aa < ndi; ++aa) {
      int di = (rowsel == 0) ? (2 * aa) : 1;
      int rro = 1 - (di >> 1);
      for (int e2 = 0; e2 < ndj; ++e2) {
        int dj = m + 4 * e2;
        float xv = sp[rro * 65 + 1 - e2];              // immediate offset (wave-uniform)
        const float* wrow = wp + (di * 7 + dj) * 50;   // wave-uniform
#pragma unroll
        for (int co = 0; co < 10; ++co)
          acc[co] = fmaf(xv, wrow[co], acc[co]);
      }
    }
  }
  float* aout = a4 + b * (50 * 16384);
#pragma unroll
  for (int co = 0; co < 10; ++co)
    aout[(co0 + co) * 16384 + i * 256 + j] = fmaxf(acc[co], 0.f);
}

// ---------------- K5a: conv5 partial over 5-ci slice (3x7 circular, 64x256) ----------
// grid (16 rowgrp, 10 cislice, 16 img) x 256 thr = 2560 blocks, single stage, 1 barrier.
__global__ __launch_bounds__(256) void k5a(const float* __restrict__ a4,
                                           const float* __restrict__ w5,
                                           float* __restrict__ p5) {
  __shared__ __align__(16) float s5[7920];   // [ci5][rr6][c264], c-8 = col mod 256
  int b = blockIdx.z;
  int r0 = blockIdx.x * 4;
  int cs = blockIdx.y;           // ci slice: [cs*5, cs*5+5)
  int tid = threadIdx.x;
  int y = tid >> 6;
  int q = tid & 63;
  int j0 = q * 4;
  float acc0 = 0.f, acc1 = 0.f, acc2 = 0.f, acc3 = 0.f;
  const float* ain = a4 + b * (50 * 16384) + cs * 5 * 16384;
  for (int e = tid; e < 7920; e += 256) {
    int ci = e / 1584;
    int rr = (e / 264) % 6;
    int c = e % 264;
    int row = (r0 - 2 + rr) & 63;
    int col = (c - 8) & 255;
    s5[e] = ain[ci * 16384 + row * 256 + col];
  }
  __syncthreads();
#pragma unroll
  for (int ci = 0; ci < 5; ++ci) {
#pragma unroll
    for (int di = 0; di < 3; ++di) {
      const float4* prow = (const float4*)&s5[ci * 1584 + (y + 2 - di) * 264 + j0];
      float4 v0 = prow[0], v1 = prow[1], v2 = prow[2];
      float wnd[12] = {v0.x, v0.y, v0.z, v0.w, v1.x, v1.y, v1.z, v1.w,
                       v2.x, v2.y, v2.z, v2.w};
      const float* wp = w5 + ((cs * 5 + ci) * 3 + di) * 7;   // wave-uniform
#pragma unroll
      for (int dj = 0; dj < 7; ++dj) {
        float wgt = wp[dj];
        acc0 = fmaf(wnd[8 - dj], wgt, acc0);
        acc1 = fmaf(wnd[9 - dj], wgt, acc1);
        acc2 = fmaf(wnd[10 - dj], wgt, acc2);
        acc3 = fmaf(wnd[11 - dj], wgt, acc3);
      }
    }
  }
  float4 r = {acc0, acc1, acc2, acc3};
  *(float4*)(p5 + (cs * 16 + b) * 16384 + (r0 + y) * 256 + j0) = r;
}

// ---------------- K5b: sum 10 partials + bias + sigmoid ------------------------------
__global__ __launch_bounds__(256) void k5b(const float* __restrict__ p5,
                                           const float* __restrict__ b5,
                                           float* __restrict__ out) {
  int i = blockIdx.x * 256 + threadIdx.x;    // 65536 float4 positions
  int b = i >> 12;                           // image
  int off = i & 4095;                        // float4 offset within image
  const float4* p4 = (const float4*)p5;
  float bias = b5[0];
  float4 s = {bias, bias, bias, bias};
#pragma unroll
  for (int cs = 0; cs < 10; ++cs) {
    float4 v = p4[(cs * 16 + b) * 4096 + off];
    s.x += v.x; s.y += v.y; s.z += v.z; s.w += v.w;
  }
  float4 r;
  r.x = 1.f / (1.f + expf(-s.x));
  r.y = 1.f / (1.f + expf(-s.y));
  r.z = 1.f / (1.f + expf(-s.z));
  r.w = 1.f / (1.f + expf(-s.w));
  ((float4*)out)[i] = r;
}

extern "C" void kernel_launch(void* const* d_in, const int* in_sizes, int n_in,
                              void* d_out, int out_size, void* d_ws, size_t ws_size,
                              hipStream_t stream) {
  (void)in_sizes; (void)n_in; (void)out_size; (void)ws_size;
  const float* x  = (const float*)d_in[0];
  const float* w1 = (const float*)d_in[1];
  const float* b1 = (const float*)d_in[2];
  const float* w2 = (const float*)d_in[3];
  const float* b2 = (const float*)d_in[4];
  const float* w3 = (const float*)d_in[5];
  const float* b3 = (const float*)d_in[6];
  const float* w4 = (const float*)d_in[7];
  const float* b4 = (const float*)d_in[8];
  const float* w5 = (const float*)d_in[9];
  const float* b5 = (const float*)d_in[10];
  float* out = (float*)d_out;
  float* ws  = (float*)d_ws;
  float* w2t = ws;                       // 52500
  float* w3t = w2t + 52500;              // 37500
  float* w4t = w3t + 37500;              // 52500
  float* a1  = w4t + 52500;              // 32*50*32*64  = 3,276,800
  float* a2  = a1 + 32 * 50 * 32 * 64;   // 32*50*16*16  = 409,600
  float* a3  = a2 + 32 * 50 * 16 * 16;   // 16*50*32*64  = 1,638,400
  float* a4  = a3 + 16 * 50 * 32 * 64;   // 16*50*64*256 = 13,107,200
  // Aliases (lifetime-disjoint): p2 lives in a4's region (dead until k4 overwrites);
  // p5 lives in a1's region (a1 dead after k2).
  float* p2  = a4;                       // 2*32*50*2048 = 6,553,600 <= 13,107,200
  float* p5  = a1;                       // 10*16*16384  = 2,621,440 <= 3,276,800
  hipLaunchKernelGGL(kprep, dim3(352), dim3(256), 0, stream, w2, w3, w4, w2t, w3t, w4t);
  hipLaunchKernelGGL(k1,  dim3(16, 5, 32), dim3(256), 0, stream, x, w1, b1, a1);
  hipLaunchKernelGGL(k2,  dim3(8, 5, 64),  dim3(256), 0, stream, a1, w2t, p2);
  hipLaunchKernelGGL(k2b, dim3(1600),      dim3(256), 0, stream, p2, b2, a2);
  hipLaunchKernelGGL(k3,  dim3(4, 10, 16), dim3(512), 0, stream, a2, w3t, b3, a3);
  hipLaunchKernelGGL(k4,  dim3(32, 5, 16), dim3(512), 0, stream, a3, w4t, b4, a4);
  hipLaunchKernelGGL(k5a, dim3(16, 10, 16), dim3(256), 0, stream, a4, w5, p5);
  hipLaunchKernelGGL(k5b, dim3(256),       dim3(256), 0, stream, p5, b5, out);
}

// Round 7
// 376.323 us; speedup vs baseline: 1.2364x; 1.0561x over previous
//
#include <hip/hip_runtime.h>
#include <math.h>

// ---------------- weight transpose: w[co][ci][kh][kw] -> wt[ci][kh][kw][co] -----------
__global__ void kprep(const float* __restrict__ w2, const float* __restrict__ w3,
                      const float* __restrict__ w4, float* __restrict__ w2t,
                      float* __restrict__ w3t, float* __restrict__ w4t) {
  int i = blockIdx.x * 256 + threadIdx.x;
  if (i < 52500) {            // w2,w4: 50*50*3*7
    int co = i % 50, r = i / 50;
    w2t[i] = w2[co * 1050 + r];
    w4t[i] = w4[co * 1050 + r];
  } else {
    int j = i - 52500;
    if (j < 37500) {          // w3: 50*50*3*5
      int co = j % 50, r = j / 50;
      w3t[j] = w3[co * 750 + r];
    }
  }
}

// ---------------- K1: conv1 (1ci->co, 3x7 circular, 64x256) + maxpool 2x4 + relu -----
__global__ __launch_bounds__(256) void k1(const float* __restrict__ x,
                                          const float* __restrict__ w1,
                                          const float* __restrict__ b1,
                                          float* __restrict__ a1) {
  int b = blockIdx.z;
  int pr0 = blockIdx.x * 2;
  int wv = __builtin_amdgcn_readfirstlane(threadIdx.x >> 6);  // 0..3
  int pc = threadIdx.x & 63;
  int pr = pr0 + (wv & 1);
  int co0 = blockIdx.y * 10 + (wv >> 1) * 5;   // SGPR
  const float* xb = x + b * (64 * 256);
  float xw[4][10];
#pragma unroll
  for (int r = 0; r < 4; ++r) {
    int row = (2 * pr - 2 + r) & 63;
#pragma unroll
    for (int c = 0; c < 10; ++c) {
      int col = (4 * pc - 6 + c) & 255;
      xw[r][c] = xb[row * 256 + col];
    }
  }
#pragma unroll
  for (int cq = 0; cq < 5; ++cq) {
    int co = co0 + cq;
    const float* wp = w1 + co * 21;      // wave-uniform -> scalar loads
    float m = -1e30f;
#pragma unroll
    for (int iy = 0; iy < 2; ++iy) {
#pragma unroll
      for (int jx = 0; jx < 4; ++jx) {
        float s = 0.f;
#pragma unroll
        for (int di = 0; di < 3; ++di)
#pragma unroll
          for (int dj = 0; dj < 7; ++dj)
            s = fmaf(xw[iy + 2 - di][jx + 6 - dj], wp[di * 7 + dj], s);
        m = fmaxf(m, s);
      }
    }
    float v = fmaxf(m + b1[co], 0.f);
    a1[((b * 50 + co) * 32 + pr) * 64 + pc] = v;
  }
}

// ---------------- K2: conv2 partial over 25-ci half (3x7 circular, 32x64) ------------
// R6 structure + padded LDS [ci][rr6][p70]: immediate-offset ds_reads, 1 vaddr per ci.
__global__ __launch_bounds__(256) void k2(const float* __restrict__ a1,
                                          const float* __restrict__ w2t,
                                          float* __restrict__ p2) {
  __shared__ float sm[4200];       // [ci<=10][rr6][p70], p-6 = col mod 64
  int hh = blockIdx.z & 1;         // ci half
  int b = blockIdx.z >> 1;         // image
  int r0 = blockIdx.x * 4;         // conv rows r0..r0+3
  int co0 = blockIdx.y * 10;
  int ci0 = hh * 25;
  int y = threadIdx.x >> 6;        // 0..3 (LDS vaddr only)
  int xcol = threadIdx.x & 63;
  float acc[10];
#pragma unroll
  for (int c = 0; c < 10; ++c) acc[c] = 0.f;
  const float* ain = a1 + b * (50 * 2048);
  for (int cc = 0; cc < 3; ++cc) {           // ci chunks {10,10,5}
    int n = (cc < 2) ? 10 : 5;
    __syncthreads();
    for (int e = threadIdx.x; e < n * 420; e += 256) {   // [ci][rr6][p70]
      int ci = e / 420;
      int rem = e - ci * 420;
      int rr = rem / 70;
      int p = rem - rr * 70;
      int row = (r0 - 2 + rr) & 31;
      int col = (p - 6) & 63;
      sm[e] = ain[(ci0 + cc * 10 + ci) * 2048 + row * 64 + col];
    }
    __syncthreads();
    for (int ci = 0; ci < n; ++ci) {
      const float* sp = sm + ci * 420 + y * 70 + xcol;   // one vaddr per ci
      const float* wbase = w2t + (ci0 + cc * 10 + ci) * 1050 + co0;
#pragma unroll
      for (int di = 0; di < 3; ++di) {
#pragma unroll
        for (int dj = 0; dj < 7; ++dj) {
          float xv = sp[(2 - di) * 70 + (6 - dj)];       // immediate offset
          const float* wrow = wbase + (di * 7 + dj) * 50;  // wave-uniform
#pragma unroll
          for (int c = 0; c < 10; ++c)
            acc[c] = fmaf(xv, wrow[c], acc[c]);
        }
      }
    }
  }
  float* pout = p2 + ((hh * 32 + b) * 50 + co0) * 2048 + (r0 + y) * 64 + xcol;
#pragma unroll
  for (int c = 0; c < 10; ++c)
    pout[c * 2048] = acc[c];
}

// ---------------- K2b: sum 2 ci-halves + bias + maxpool 2x4 + relu -------------------
__global__ __launch_bounds__(256) void k2b(const float* __restrict__ p2,
                                           const float* __restrict__ b2,
                                           float* __restrict__ a2) {
  int idx = blockIdx.x * 256 + threadIdx.x;  // 409600 outputs
  int pc = idx & 15;
  int pr = (idx >> 4) & 15;
  int t = idx >> 8;
  int co = t % 50;
  int b = t / 50;
  int i0 = ((b) * 50 + co) * 2048 + (2 * pr) * 64 + 4 * pc;
  int i1 = i0 + 32 * 50 * 2048;
  float bias = b2[co];
  float m = -1e30f;
#pragma unroll
  for (int yy = 0; yy < 2; ++yy)
#pragma unroll
    for (int xx = 0; xx < 4; ++xx) {
      int o = yy * 64 + xx;
      m = fmaxf(m, p2[i0 + o] + p2[i1 + o] + bias);
    }
  a2[((b * 50 + co) * 16 + pr) * 16 + pc] = fmaxf(m, 0.f);
}

// ---------------- K3: combine(even + mean(odd)) -> upsample(2,4)-sparse conv3 (3x5) + relu
__global__ __launch_bounds__(512) void k3(const float* __restrict__ a2,
                                          const float* __restrict__ w3t,
                                          const float* __restrict__ b3,
                                          float* __restrict__ a3) {
  __shared__ float ts[4250];     // [ci50][rr5][p17], p-1 = col mod 16
  __shared__ float mean_s[64];
  __shared__ float part[200];
  int b = blockIdx.z;
  int r0 = blockIdx.x * 8;       // output rows r0..r0+7
  int co0 = blockIdx.y * 5;
  int tid = threadIdx.x;
  const float* aodd = a2 + (2 * b + 1) * (50 * 256);
  if (tid < 200) {
    int ci = tid >> 2, pp = tid & 3;
    float s = 0.f;
    for (int k = 0; k < 64; ++k) s += aodd[ci * 256 + pp * 64 + k];
    part[tid] = s;
  }
  __syncthreads();
  if (tid < 50)
    mean_s[tid] = (part[4 * tid] + part[4 * tid + 1] + part[4 * tid + 2] + part[4 * tid + 3]) * (1.f / 256.f);
  __syncthreads();
  const float* aev = a2 + (2 * b) * (50 * 256);
  for (int e = tid; e < 4250; e += 512) {
    int ci = e / 85;
    int rem = e - ci * 85;
    int rr = rem / 17;
    int p = rem - rr * 17;
    int trow = ((r0 >> 1) - 1 + rr) & 15;
    int col = (p - 1) & 15;
    ts[e] = aev[ci * 256 + trow * 16 + col] + mean_s[ci];
  }
  __syncthreads();
  int wv = __builtin_amdgcn_readfirstlane(tid >> 6);   // 0..7
  int lane = tid & 63;
  int pcls = wv >> 2;            // row parity class (SGPR)
  int m = wv & 3;                // j%4 class (SGPR)
  int q = lane & 15;
  int yidx = lane >> 4;
  int i = r0 + 2 * yidx + pcls;
  int j = 4 * q + m;
  float acc[5];
#pragma unroll
  for (int c = 0; c < 5; ++c) acc[c] = b3[co0 + c];
  int ndi = (pcls == 0) ? 2 : 1;
  int ndj = (m == 0) ? 2 : 1;
  for (int ci = 0; ci < 50; ++ci) {
    const float* sp = ts + ci * 85 + yidx * 17 + q;    // one vaddr per ci
    const float* wp = w3t + ci * 750 + co0;
    for (int aa = 0; aa < ndi; ++aa) {
      int di = (pcls == 0) ? (2 * aa) : 1;
      int rro = 1 - (di >> 1);
      for (int e2 = 0; e2 < ndj; ++e2) {
        int dj = (m == 0) ? (4 * e2) : m;
        float xv = sp[rro * 17 + 1 - e2];              // immediate offset (wave-uniform)
        const float* wrow = wp + (di * 5 + dj) * 50;   // wave-uniform
#pragma unroll
        for (int c = 0; c < 5; ++c)
          acc[c] = fmaf(xv, wrow[c], acc[c]);
      }
    }
  }
  float* aout = a3 + b * (50 * 2048);
#pragma unroll
  for (int c = 0; c < 5; ++c)
    aout[(co0 + c) * 2048 + i * 64 + j] = fmaxf(acc[c], 0.f);
}

// ---------------- K4: upsample(2,4)-sparse conv4 (3x7, 64x256) + relu ----------------
// Balanced design: each thread owns a 1x4 output strip (all j%4 in-thread, tap->acc
// routing m=dj&3, tc=q-(dj>>2)). Even-row waves: di{0,2}x7 taps x 5 co = 70 FMA/ci;
// odd-row waves: di{1}x7 x 10 co = 70 FMA/ci -> zero imbalance. 6 waves/block
// (2 rowpairs x {even-lo5, even-hi5, odd10}), 39 KB LDS, float4 stores.
__global__ __launch_bounds__(384) void k4(const float* __restrict__ a3,
                                          const float* __restrict__ w4t,
                                          const float* __restrict__ b4,
                                          float* __restrict__ a4) {
  __shared__ float s4[9750];     // [ci50][rr3][p65], rr = inrow-(rp0-1), p-1 = col mod 64
  int b = blockIdx.z;
  int r0 = blockIdx.x * 4;       // output rows r0..r0+3
  int co0 = blockIdx.y * 10;
  int rp0 = r0 >> 1;
  int tid = threadIdx.x;
  const float* ain = a3 + b * (50 * 2048);
  for (int e = tid; e < 9750; e += 384) {
    int ci = e / 195;
    int rem = e - ci * 195;
    int rr = rem / 65;
    int p = rem - rr * 65;
    int row = (rp0 - 1 + rr) & 31;
    int col = (p - 1) & 63;
    s4[e] = ain[ci * 2048 + row * 64 + col];
  }
  __syncthreads();
  int wv = __builtin_amdgcn_readfirstlane(tid >> 6);  // 0..5
  int q = tid & 63;
  int g = (wv >= 3) ? 1 : 0;      // rowpair
  int wl = wv - 3 * g;            // 0,1,2
  int orow = r0 + 2 * g + ((wl == 2) ? 1 : 0);
  int cobase = co0 + ((wl == 1) ? 5 : 0);
  float acc[4][10];
  if (wl < 2) {
    // even output row: di in {0,2}; rr(di=0)=g+1, rr(di=2)=g; 5 co
#pragma unroll
    for (int m = 0; m < 4; ++m)
#pragma unroll
      for (int c = 0; c < 5; ++c) acc[m][c] = b4[cobase + c];
#pragma unroll 1
    for (int ci = 0; ci < 50; ++ci) {
      const float* sp = s4 + ci * 195 + q;     // one vaddr per ci
      float x0lo = sp[(g + 1) * 65];           // di=0, col q-1
      float x0hi = sp[(g + 1) * 65 + 1];       // di=0, col q
      float x2lo = sp[g * 65];                 // di=2, col q-1
      float x2hi = sp[g * 65 + 1];             // di=2, col q
      const float* wp = w4t + ci * 1050 + cobase;
#pragma unroll
      for (int dj = 0; dj < 7; ++dj) {
        int m = dj & 3;
        float xv0 = (dj < 4) ? x0hi : x0lo;
        float xv2 = (dj < 4) ? x2hi : x2lo;
        const float* w0 = wp + dj * 50;              // di=0, wave-uniform
        const float* w2 = wp + (14 + dj) * 50;       // di=2
#pragma unroll
        for (int c = 0; c < 5; ++c) {
          acc[m][c] = fmaf(xv0, w0[c], acc[m][c]);
          acc[m][c] = fmaf(xv2, w2[c], acc[m][c]);
        }
      }
    }
    float* aout = a4 + b * (50 * 16384) + orow * 256 + 4 * q;
#pragma unroll
    for (int c = 0; c < 5; ++c) {
      float4 v;
      v.x = fmaxf(acc[0][c], 0.f);
      v.y = fmaxf(acc[1][c], 0.f);
      v.z = fmaxf(acc[2][c], 0.f);
      v.w = fmaxf(acc[3][c], 0.f);
      *(float4*)(aout + (cobase - co0 + c + co0) * 16384) = v;
      aout += 0;  // (address computed per c below via offset)
      aout = a4 + b * (50 * 16384) + orow * 256 + 4 * q;  // keep base stable
      *(float4*)(a4 + b * (50 * 16384) + (cobase + c) * 16384 + orow * 256 + 4 * q) = v;
    }
  } else {
    // odd output row: di=1; rr=g+1; 10 co
#pragma unroll
    for (int m = 0; m < 4; ++m)
#pragma unroll
      for (int c = 0; c < 10; ++c) acc[m][c] = b4[cobase + c];
#pragma unroll 1
    for (int ci = 0; ci < 50; ++ci) {
      const float* sp = s4 + ci * 195 + (g + 1) * 65 + q;
      float xlo = sp[0];                       // col q-1
      float xhi = sp[1];                       // col q
      const float* wp = w4t + ci * 1050 + 7 * 50 + cobase;   // di=1
#pragma unroll
      for (int dj = 0; dj < 7; ++dj) {
        int m = dj & 3;
        float xv = (dj < 4) ? xhi : xlo;
        const float* w1r = wp + dj * 50;             // wave-uniform
#pragma unroll
        for (int c = 0; c < 10; ++c)
          acc[m][c] = fmaf(xv, w1r[c], acc[m][c]);
      }
    }
#pragma unroll
    for (int c = 0; c < 10; ++c) {
      float4 v;
      v.x = fmaxf(acc[0][c], 0.f);
      v.y = fmaxf(acc[1][c], 0.f);
      v.z = fmaxf(acc[2][c], 0.f);
      v.w = fmaxf(acc[3][c], 0.f);
      *(float4*)(a4 + b * (50 * 16384) + (cobase + c) * 16384 + orow * 256 + 4 * q) = v;
    }
  }
}

// ---------------- K5a: conv5 partial over 5-ci slice (3x7 circular, 64x256) ----------
__global__ __launch_bounds__(256) void k5a(const float* __restrict__ a4,
                                           const float* __restrict__ w5,
                                           float* __restrict__ p5) {
  __shared__ __align__(16) float s5[7920];   // [ci5][rr6][c264], c-8 = col mod 256
  int b = blockIdx.z;
  int r0 = blockIdx.x * 4;
  int cs = blockIdx.y;           // ci slice: [cs*5, cs*5+5)
  int tid = threadIdx.x;
  int y = tid >> 6;
  int q = tid & 63;
  int j0 = q * 4;
  float acc0 = 0.f, acc1 = 0.f, acc2 = 0.f, acc3 = 0.f;
  const float* ain = a4 + b * (50 * 16384) + cs * 5 * 16384;
  for (int e = tid; e < 7920; e += 256) {
    int ci = e / 1584;
    int rr = (e / 264) % 6;
    int c = e % 264;
    int row = (r0 - 2 + rr) & 63;
    int col = (c - 8) & 255;
    s5[e] = ain[ci * 16384 + row * 256 + col];
  }
  __syncthreads();
#pragma unroll
  for (int ci = 0; ci < 5; ++ci) {
#pragma unroll
    for (int di = 0; di < 3; ++di) {
      const float4* prow = (const float4*)&s5[ci * 1584 + (y + 2 - di) * 264 + j0];
      float4 v0 = prow[0], v1 = prow[1], v2 = prow[2];
      float wnd[12] = {v0.x, v0.y, v0.z, v0.w, v1.x, v1.y, v1.z, v1.w,
                       v2.x, v2.y, v2.z, v2.w};
      const float* wp = w5 + ((cs * 5 + ci) * 3 + di) * 7;   // wave-uniform
#pragma unroll
      for (int dj = 0; dj < 7; ++dj) {
        float wgt = wp[dj];
        acc0 = fmaf(wnd[8 - dj], wgt, acc0);
        acc1 = fmaf(wnd[9 - dj], wgt, acc1);
        acc2 = fmaf(wnd[10 - dj], wgt, acc2);
        acc3 = fmaf(wnd[11 - dj], wgt, acc3);
      }
    }
  }
  float4 r = {acc0, acc1, acc2, acc3};
  *(float4*)(p5 + (cs * 16 + b) * 16384 + (r0 + y) * 256 + j0) = r;
}

// ---------------- K5b: sum 10 partials + bias + sigmoid ------------------------------
__global__ __launch_bounds__(256) void k5b(const float* __restrict__ p5,
                                           const float* __restrict__ b5,
                                           float* __restrict__ out) {
  int i = blockIdx.x * 256 + threadIdx.x;    // 65536 float4 positions
  int b = i >> 12;                           // image
  int off = i & 4095;                        // float4 offset within image
  const float4* p4 = (const float4*)p5;
  float bias = b5[0];
  float4 s = {bias, bias, bias, bias};
#pragma unroll
  for (int cs = 0; cs < 10; ++cs) {
    float4 v = p4[(cs * 16 + b) * 4096 + off];
    s.x += v.x; s.y += v.y; s.z += v.z; s.w += v.w;
  }
  float4 r;
  r.x = 1.f / (1.f + expf(-s.x));
  r.y = 1.f / (1.f + expf(-s.y));
  r.z = 1.f / (1.f + expf(-s.z));
  r.w = 1.f / (1.f + expf(-s.w));
  ((float4*)out)[i] = r;
}

extern "C" void kernel_launch(void* const* d_in, const int* in_sizes, int n_in,
                              void* d_out, int out_size, void* d_ws, size_t ws_size,
                              hipStream_t stream) {
  (void)in_sizes; (void)n_in; (void)out_size; (void)ws_size;
  const float* x  = (const float*)d_in[0];
  const float* w1 = (const float*)d_in[1];
  const float* b1 = (const float*)d_in[2];
  const float* w2 = (const float*)d_in[3];
  const float* b2 = (const float*)d_in[4];
  const float* w3 = (const float*)d_in[5];
  const float* b3 = (const float*)d_in[6];
  const float* w4 = (const float*)d_in[7];
  const float* b4 = (const float*)d_in[8];
  const float* w5 = (const float*)d_in[9];
  const float* b5 = (const float*)d_in[10];
  float* out = (float*)d_out;
  float* ws  = (float*)d_ws;
  float* w2t = ws;                       // 52500
  float* w3t = w2t + 52500;              // 37500
  float* w4t = w3t + 37500;              // 52500
  float* a1  = w4t + 52500;              // 32*50*32*64  = 3,276,800
  float* a2  = a1 + 32 * 50 * 32 * 64;   // 32*50*16*16  = 409,600
  float* a3  = a2 + 32 * 50 * 16 * 16;   // 16*50*32*64  = 1,638,400
  float* a4  = a3 + 16 * 50 * 32 * 64;   // 16*50*64*256 = 13,107,200
  // Aliases (lifetime-disjoint): p2 lives in a4's region (dead until k4 overwrites);
  // p5 lives in a1's region (a1 dead after k2).
  float* p2  = a4;                       // 2*32*50*2048 = 6,553,600 <= 13,107,200
  float* p5  = a1;                       // 10*16*16384  = 2,621,440 <= 3,276,800
  hipLaunchKernelGGL(kprep, dim3(352), dim3(256), 0, stream, w2, w3, w4, w2t, w3t, w4t);
  hipLaunchKernelGGL(k1,  dim3(16, 5, 32), dim3(256), 0, stream, x, w1, b1, a1);
  hipLaunchKernelGGL(k2,  dim3(8, 5, 64),  dim3(256), 0, stream, a1, w2t, p2);
  hipLaunchKernelGGL(k2b, dim3(1600),      dim3(256), 0, stream, p2, b2, a2);
  hipLaunchKernelGGL(k3,  dim3(4, 10, 16), dim3(512), 0, stream, a2, w3t, b3, a3);
  hipLaunchKernelGGL(k4,  dim3(16, 5, 16), dim3(384), 0, stream, a3, w4t, b4, a4);
  hipLaunchKernelGGL(k5a, dim3(16, 10, 16), dim3(256), 0, stream, a4, w5, p5);
  hipLaunchKernelGGL(k5b, dim3(256),       dim3(256), 0, stream, p5, b5, out);
}